// Round 13
// baseline (80.898 us; speedup 1.0000x reference)
//
#include <hip/hip_runtime.h>
#include <hip/hip_bf16.h>

typedef _Float16 f16x8 __attribute__((ext_vector_type(8)));
typedef float f32x4 __attribute__((ext_vector_type(4)));

#define BB 8
#define NN 20
#define KK 5
#define DD 230
#define NQ 200

#define NB_TR 207    // transpose 230x230 -> Wt[230][232]
#define NB_B  200    // build fragment-packed B + epilogue table
#define NB_CONV 575  // 575 M-tiles (64 rows each), full N=320 per block
#define NB_FCB 1200  // 2400 rows / 2 per block
#define NB_ATT 800
#define NB_CP 90     // 46000 float4 / 512

// ============ k_pre: fc_w transpose + fragment-packed im2col B ============
// Bp element (tile nt 0..19, ks 0..4, ncl 0..15, kg 0..31):
//   Bp[((nt*5+ks)*16+ncl)*32+kg] = Bmat[n=nt*16+ncl][k=ks*32+kg]
//   Bmat[n][k]: o=n/5, i=n%5, c=k/5, j=k%5, t=j-i+2; w2[o][c][t] if 0<=t<5
__global__ void k_pre(const float* __restrict__ fc_w, float* __restrict__ Wt,
                      const float* __restrict__ w2, const float* __restrict__ b2,
                      const float* __restrict__ wf,
                      _Float16* __restrict__ Bp, float2* __restrict__ tblg) {
    const int bid = blockIdx.x, tid = threadIdx.x;
    if (bid < NB_TR) {
        int idx = bid * 256 + tid;
        if (idx < DD * DD) {
            int i = idx / DD, j = idx - (idx / DD) * DD;
            Wt[j * 232 + i] = fc_w[idx];
        }
    } else {
        int g = (bid - NB_TR) * 256 + tid;   // < 51200 exactly
        int kg = g & 31;
        int ncl = (g >> 5) & 15;
        int tk = g >> 9;                     // nt*5+ks, 0..99
        int nt = tk / 5, ks = tk - nt * 5;
        int n = nt * 16 + ncl, k = ks * 32 + kg;
        int o = n / 5, i = n % 5;
        int c = k / 5, j = k - c * 5;
        int t = j - i + 2;
        float val = (t >= 0 && t < 5) ? w2[(o * 32 + c) * 5 + t] : 0.f;
        Bp[g] = (_Float16)val;
        if (g < 320) {
            int o2 = g / 5, i2 = g % 5;
            tblg[g] = make_float2(b2[o2], wf[o2 * 5 + i2]);
        }
    }
}

// ============ k_main: conv-as-MFMA (0..574) + fc k-split (575..1774) ============
__global__ __launch_bounds__(512)
void k_main(const float* __restrict__ S, const float* __restrict__ Q,
            const float* __restrict__ w1, const float* __restrict__ b1,
            const _Float16* __restrict__ Bp, const float2* __restrict__ tblg,
            float* __restrict__ sc,
            const float* __restrict__ Wt, const float* __restrict__ fc_b,
            float* __restrict__ Sf, float* __restrict__ Qf) {
    __shared__ __align__(16) _Float16 Xs[64 * 168];   // 21504 B
    __shared__ float xfp[8][16];                      //   512 B
    __shared__ __align__(16) f32x4 xfc[8][58];        //  7424 B
    const int bid = blockIdx.x, tid = threadIdx.x;
    const int lane = tid & 63;
    const int w = __builtin_amdgcn_readfirstlane(tid >> 6);   // 0..7 uniform

    if (bid >= NB_CONV) {
        // ---- fc: 2 rows/block; wave = (row = w>>2, k-slice = w&3 of ~58) ----
        const int row = (bid - NB_CONV) * 2 + (w >> 2);
        const int wsl = w & 3;
        const float* inp;
        float* outp;
        float scale;
        if (row < BB * NN * KK) {
            inp = S + (size_t)row * DD;
            outp = Sf + (size_t)row * DD;
            scale = 2.8853900817779268f;   // 2*log2(e)
        } else {
            int r = row - BB * NN * KK;
            inp = Q + (size_t)r * DD;
            outp = Qf + (size_t)r * DD;
            scale = 1.0f;
        }
        const f32x4* WT4 = (const f32x4*)Wt;    // 58 float4 per k-row
        const int cl = lane < 58 ? lane : 57;
        const int k0 = wsl * 58;
        const int k1 = (wsl == 3) ? 230 : (k0 + 58);
        f32x4 a = {0.f, 0.f, 0.f, 0.f};
        for (int k = k0; k < k1; k++)
            a += inp[k] * WT4[k * 58 + cl];
        xfc[w][cl] = a;
        __syncthreads();
        if ((w & 3) == 0 && lane < 58) {
            f32x4 s4 = xfc[w][lane] + xfc[w + 1][lane]
                     + xfc[w + 2][lane] + xfc[w + 3][lane];
            const int c0 = lane * 4;
#pragma unroll
            for (int jj = 0; jj < 4; jj++) {
                int c = c0 + jj;
                if (c < DD) outp[c] = (s4[jj] + fc_b[c]) * scale;
            }
        }
        return;
    }

    // ---- conv: 64 M-rows; wave w = (msub = w&3, ngrp = w>>2) ----
    const int m0 = bid * 64;

    // conv1: row = lane, channels c = w*4..w*4+3
    {
        const int m = m0 + lane;
        const int img = m / DD;
        const int d = m - img * DD;
        const float* sp = S + (size_t)img * KK * DD + d;
        float in5[5];
#pragma unroll
        for (int j = 0; j < 5; j++) in5[j] = sp[j * DD];
#pragma unroll
        for (int cc = 0; cc < 4; cc++) {
            int c = w * 4 + cc;
            float wl[5];
#pragma unroll
            for (int t = 0; t < 5; t++) wl[t] = w1[c * 5 + t];
            float bb = b1[c];
#pragma unroll
            for (int i = 0; i < 5; i++) {
                float a = bb;
#pragma unroll
                for (int t = 0; t < 5; t++) {
                    int j = i + t - 2;
                    if (j >= 0 && j < 5) a = fmaf(wl[t], in5[j], a);
                }
                Xs[lane * 168 + c * 5 + i] = (_Float16)fmaxf(a, 0.f);
            }
        }
    }
    __syncthreads();

    const int msub = w & 3;
    const int gq = w >> 2;          // n-group: tiles gq*10 .. gq*10+9
    const int ncl = lane & 15;
    const int kg8 = (lane >> 4) * 8;
    const int g4 = lane >> 4;

    // A-operand (X fragments) for this wave's m-sub, reused across all tiles
    f16x8 af[5];
#pragma unroll
    for (int ks = 0; ks < 5; ks++)
        af[ks] = *(const f16x8*)&Xs[(msub * 16 + ncl) * 168 + ks * 32 + kg8];

    float xf = 0.f;
    for (int t10 = 0; t10 < 10; t10++) {
        const int nt = gq * 10 + t10;            // global tile 0..19
        const _Float16* bp = Bp + ((size_t)nt * 5 * 16) * 32;
        f32x4 a = {0.f, 0.f, 0.f, 0.f};
#pragma unroll
        for (int ks = 0; ks < 5; ks++) {
            f16x8 br = *(const f16x8*)&bp[((ks * 16) + ncl) * 32 + kg8];
            a = __builtin_amdgcn_mfma_f32_16x16x32_f16(br, af[ks], a, 0, 0, 0);
        }
        // D[n][m]: lane holds m-col = ncl, n-rows = nt*16 + g4*4 + r
        float2 tb[4];
#pragma unroll
        for (int r = 0; r < 4; r++) tb[r] = tblg[nt * 16 + g4 * 4 + r];
#pragma unroll
        for (int r = 0; r < 4; r++)
            xf = fmaf(fmaxf(a[r] + tb[r].x, 0.f), tb[r].y, xf);
    }
    // reduce over g4 groups (lanes differing in bits 4,5)
    xf += __shfl_xor(xf, 16, 64);
    xf += __shfl_xor(xf, 32, 64);
    if (lane < 16) xfp[w][lane] = xf;
    __syncthreads();
    if (tid < 64) {
        const int ms = tid >> 4, j = tid & 15;
        sc[m0 + ms * 16 + j] = xfp[ms][j] + xfp[ms + 4][j];
    }
}

// ============ k_att: att (0..799) + S-copy (800..889); 512 thr ============
__global__ __launch_bounds__(512)
void k_att(const float* __restrict__ Sf, const float* __restrict__ Qf,
           const float* __restrict__ S, const float* __restrict__ Q,
           const float* __restrict__ sc, const float* __restrict__ convf_b,
           float* __restrict__ out, float* __restrict__ Scopy) {
    __shared__ float Sft[25][232];
    __shared__ float Ls[8][25];
    const int bid = blockIdx.x, tid = threadIdx.x;
    if (bid >= NB_ATT) {
        int g = (bid - NB_ATT) * 512 + tid;
        if (g < 46000) ((float4*)Scopy)[g] = ((const float4*)S)[g];
        return;
    }
    const int lane = tid & 63, wv = tid >> 6;   // wv 0..7
    const int qg = bid % 25;
    const int nq = (bid / 25) & 3;
    const int b  = bid / 100;
    const int q  = qg * 8 + wv, n0 = nq * 5;
    const float LOG2E = 1.4426950408889634f;
    const float bf0 = convf_b[0];

    const float* sfb = Sf + ((size_t)b * 100 + n0 * 5) * DD;
    for (int e = tid; e < 25 * DD; e += 512) Sft[e / DD][e % DD] = sfb[e];
    __syncthreads();

    float qf[4];
    const float* qfp = Qf + ((size_t)b * NQ + q) * DD;
#pragma unroll
    for (int i = 0; i < 4; i++) {
        int d = lane + 64 * i;
        qf[i] = (d < DD) ? qfp[d] : 0.f;
    }
    for (int idx = 0; idx < 25; idx++) {
        float racc = 0.f;
#pragma unroll
        for (int i = 0; i < 4; i++) {
            int d = lane + 64 * i;
            float s = (d < DD) ? Sft[idx][d] : 0.f;
            float e = __builtin_amdgcn_exp2f(s * qf[i]);
            racc += __builtin_amdgcn_rcpf(e + 1.f);
        }
#pragma unroll
        for (int off = 32; off > 0; off >>= 1) racc += __shfl_xor(racc, off, 64);
        if (lane == 0) Ls[wv][idx] = fmaf(-2.f, racc, 256.f);
    }

    float qr[4];
    const float* qp = Q + ((size_t)b * NQ + q) * DD;
#pragma unroll
    for (int i = 0; i < 4; i++) {
        int d = lane + 64 * i;
        qr[i] = (d < DD) ? qp[d] : 0.f;
    }
    for (int nl = 0; nl < 5; nl++) {
        const float* lp = Ls[wv] + nl * 5;
        float v0 = lp[0], v1 = lp[1], v2 = lp[2], v3 = lp[3], v4 = lp[4];
        float m = fmaxf(fmaxf(fmaxf(v0, v1), fmaxf(v2, v3)), v4);
        float e0 = __builtin_amdgcn_exp2f((v0 - m) * LOG2E);
        float e1 = __builtin_amdgcn_exp2f((v1 - m) * LOG2E);
        float e2 = __builtin_amdgcn_exp2f((v2 - m) * LOG2E);
        float e3 = __builtin_amdgcn_exp2f((v3 - m) * LOG2E);
        float e4 = __builtin_amdgcn_exp2f((v4 - m) * LOG2E);
        float inv = __builtin_amdgcn_rcpf(e0 + e1 + e2 + e3 + e4);
        float a0 = e0 * inv, a1 = e1 * inv, a2 = e2 * inv, a3 = e3 * inv, a4 = e4 * inv;
        const int n = n0 + nl;
        const float* spn = S + (size_t)(b * NN + n) * KK * DD;
        const float* s0 = sc + (size_t)(b * NN + n) * DD;
        float acc = 0.f;
#pragma unroll
        for (int i = 0; i < 4; i++) {
            int d = lane + 64 * i;
            if (d < DD) {
                float rep = a0 * spn[d] + a1 * spn[DD + d] + a2 * spn[2 * DD + d]
                          + a3 * spn[3 * DD + d] + a4 * spn[4 * DD + d];
                float df = rep - qr[i];
                float scw = fmaxf(s0[d] + bf0, 0.f) * 700.f;
                acc = fmaf(df * df, scw, acc);
            }
        }
#pragma unroll
        for (int off = 32; off > 0; off >>= 1) acc += __shfl_xor(acc, off, 64);
        if (lane == 0) out[((size_t)b * NQ + q) * NN + n] = -acc;
    }
}

extern "C" void kernel_launch(void* const* d_in, const int* in_sizes, int n_in,
                              void* d_out, int out_size, void* d_ws, size_t ws_size,
                              hipStream_t stream) {
    const float* S       = (const float*)d_in[0];
    const float* Q       = (const float*)d_in[1];
    const float* fc_w    = (const float*)d_in[2];
    const float* fc_b    = (const float*)d_in[3];
    const float* conv1_w = (const float*)d_in[4];
    const float* conv1_b = (const float*)d_in[5];
    const float* conv2_w = (const float*)d_in[6];
    const float* conv2_b = (const float*)d_in[7];
    const float* convf_w = (const float*)d_in[8];
    const float* convf_b = (const float*)d_in[9];
    float* out = (float*)d_out;

    float* ws = (float*)d_ws;
    float* Wt  = ws;                               // 53824 dwords
    float* Sf  = Wt + 53824;                       // 184000
    float* Qf  = Sf + 184000;                      // 368000
    float* sc  = Qf + 368000;                      // 36800
    _Float16* Bp = (_Float16*)(sc + 36800);        // 25600 dwords
    float2* tblg = (float2*)(sc + 36800 + 25600);  // 640 dwords

    k_pre<<<NB_TR + NB_B, 256, 0, stream>>>(
        fc_w, Wt, conv2_w, conv2_b, convf_w, Bp, tblg);
    k_main<<<NB_CONV + NB_FCB, 512, 0, stream>>>(
        S, Q, conv1_w, conv1_b, Bp, tblg, sc, Wt, fc_b, Sf, Qf);
    k_att<<<NB_ATT + NB_CP, 512, 0, stream>>>(
        Sf, Qf, S, Q, sc, convf_b, out, out + (size_t)BB * NQ * NN);
}

// Round 14
// 75.775 us; speedup vs baseline: 1.0676x; 1.0676x over previous
//
#include <hip/hip_runtime.h>
#include <hip/hip_bf16.h>

typedef _Float16 f16x8 __attribute__((ext_vector_type(8)));
typedef float f32x4 __attribute__((ext_vector_type(4)));

#define BB 8
#define NN 20
#define KK 5
#define DD 230
#define NQ 200

#define NB_BFC 240   // build Bfc: 61440 f16 fc fragments
#define NB_BP  200   // build Bp: 51200 f16 conv fragments + tblg
#define NB_CONV 575  // conv M-tiles (64 rows)
#define NB_FC2 38    // fc M-tiles (64 rows): 2400 rows
#define NB_ATT 800
#define NB_CP 90     // 46000 float4 / 512

// ============ k_pre: fragment-packed Bfc (fc) + Bp (conv) + tables ============
// Bfc[((nt*8+ks)*16+ncl)*32+kg] = fc_w[n][k], n=nt*16+ncl, k=ks*32+kg (0 pad)
// Bp [((nt*5+ks)*16+ncl)*32+kg] = im2col conv2 weights (R13 layout)
__global__ void k_pre(const float* __restrict__ fc_w,
                      const float* __restrict__ w2, const float* __restrict__ b2,
                      const float* __restrict__ wf,
                      _Float16* __restrict__ Bfc, _Float16* __restrict__ Bp,
                      float2* __restrict__ tblg) {
    const int bid = blockIdx.x, tid = threadIdx.x;
    if (bid < NB_BFC) {
        int g = bid * 256 + tid;             // < 61440
        int kg = g & 31;
        int ncl = (g >> 5) & 15;
        int tk = g >> 9;                     // nt*8+ks, 0..119
        int nt = tk >> 3, ks = tk & 7;
        int n = nt * 16 + ncl, k = ks * 32 + kg;
        float val = (n < DD && k < DD) ? fc_w[n * DD + k] : 0.f;
        Bfc[g] = (_Float16)val;
    } else {
        int g = (bid - NB_BFC) * 256 + tid;  // < 51200
        int kg = g & 31;
        int ncl = (g >> 5) & 15;
        int tk = g >> 9;                     // nt*5+ks, 0..99
        int nt = tk / 5, ks = tk - nt * 5;
        int n = nt * 16 + ncl, k = ks * 32 + kg;
        int o = n / 5, i = n % 5;
        int c = k / 5, j = k - c * 5;
        int t = j - i + 2;
        float val = (t >= 0 && t < 5) ? w2[(o * 32 + c) * 5 + t] : 0.f;
        Bp[g] = (_Float16)val;
        if (g < 320) {
            int o2 = g / 5, i2 = g % 5;
            tblg[g] = make_float2(b2[o2], wf[o2 * 5 + i2]);
        }
    }
}

// ============ k_main: conv-as-MFMA (0..574) + fc-as-MFMA (575..612) ============
__global__ __launch_bounds__(512)
void k_main(const float* __restrict__ S, const float* __restrict__ Q,
            const float* __restrict__ w1, const float* __restrict__ b1,
            const _Float16* __restrict__ Bp, const _Float16* __restrict__ Bfc,
            const float2* __restrict__ tblg, float* __restrict__ sc,
            const float* __restrict__ fc_b,
            float* __restrict__ Sf, float* __restrict__ Qf) {
    __shared__ __align__(16) _Float16 XU[64 * 264];   // conv: stride 168; fc: 264
    __shared__ float xfp[8][16];
    const int bid = blockIdx.x, tid = threadIdx.x;
    const int lane = tid & 63;
    const int w = __builtin_amdgcn_readfirstlane(tid >> 6);   // 0..7 uniform
    const int ncl = lane & 15;
    const int kg8 = (lane >> 4) * 8;
    const int g4 = lane >> 4;

    if (bid >= NB_CONV) {
        // ---- fc GEMM: 64 rows (S rows 0..799 then Q rows 800..2399) ----
        const int m0 = (bid - NB_CONV) * 64;
        // stage A rows as f16, stride 264, k-pad 230..263 zeroed
        for (int e = tid; e < 64 * 58; e += 512) {
            int row = e / 58, c4 = e - row * 58;
            int grow = m0 + row;
            float4 v = make_float4(0.f, 0.f, 0.f, 0.f);
            if (grow < 2400) {
                const float* inp = (grow < 800) ? S + (size_t)grow * DD
                                                : Q + (size_t)(grow - 800) * DD;
                if (c4 < 57) v = *(const float4*)&inp[c4 * 4];
                else { v.x = inp[228]; v.y = inp[229]; }
            }
            _Float16* xp = &XU[row * 264 + c4 * 4];
            xp[0] = (_Float16)v.x; xp[1] = (_Float16)v.y;
            xp[2] = (_Float16)v.z; xp[3] = (_Float16)v.w;
        }
        for (int e = tid; e < 64 * 16; e += 512) {
            int row = e >> 4, cc = 232 + (e & 15) * 2;
            *(unsigned int*)&XU[row * 264 + cc] = 0u;
        }
        __syncthreads();

        const int msub = w & 3;           // 16-row strip
        const int ngrp = w >> 2;          // 0: tiles 0..7, 1: tiles 8..14
        f16x8 af[8];
#pragma unroll
        for (int ks = 0; ks < 8; ks++)
            af[ks] = *(const f16x8*)&XU[(msub * 16 + ncl) * 264 + ks * 32 + kg8];

        const int nt0 = ngrp * 8;
        const int ntn = ngrp ? 7 : 8;
        for (int ti = 0; ti < ntn; ti++) {
            const int nt = nt0 + ti;
            const _Float16* bp = Bfc + ((size_t)nt * 8 * 16) * 32;
            f32x4 a = {0.f, 0.f, 0.f, 0.f};
#pragma unroll
            for (int ks = 0; ks < 8; ks++) {
                f16x8 br = *(const f16x8*)&bp[(ks * 16 + ncl) * 32 + kg8];
                a = __builtin_amdgcn_mfma_f32_16x16x32_f16(af[ks], br, a, 0, 0, 0);
            }
            // D[m][n]: lane holds col n = nt*16+ncl, rows m = msub*16 + g4*4 + r
            const int n = nt * 16 + ncl;
            const float bias = fc_b[n < DD ? n : DD - 1];
            if (n < DD) {
#pragma unroll
                for (int r = 0; r < 4; r++) {
                    int grow = m0 + msub * 16 + g4 * 4 + r;
                    if (grow < 800)
                        Sf[(size_t)grow * DD + n] = (a[r] + bias) * 2.8853900817779268f;
                    else if (grow < 2400)
                        Qf[(size_t)(grow - 800) * DD + n] = a[r] + bias;
                }
            }
        }
        return;
    }

    // ---- conv: 64 M-rows; wave w = (msub = w&3, ngrp = w>>2) ----
    const int m0 = bid * 64;
    {
        const int m = m0 + lane;
        const int img = m / DD;
        const int d = m - img * DD;
        const float* sp = S + (size_t)img * KK * DD + d;
        float in5[5];
#pragma unroll
        for (int j = 0; j < 5; j++) in5[j] = sp[j * DD];
#pragma unroll
        for (int cc = 0; cc < 4; cc++) {
            int c = w * 4 + cc;
            float wl[5];
#pragma unroll
            for (int t = 0; t < 5; t++) wl[t] = w1[c * 5 + t];
            float bb = b1[c];
#pragma unroll
            for (int i = 0; i < 5; i++) {
                float a = bb;
#pragma unroll
                for (int t = 0; t < 5; t++) {
                    int j = i + t - 2;
                    if (j >= 0 && j < 5) a = fmaf(wl[t], in5[j], a);
                }
                XU[lane * 168 + c * 5 + i] = (_Float16)fmaxf(a, 0.f);
            }
        }
    }
    __syncthreads();

    const int msub = w & 3;
    const int gq = w >> 2;          // n-group: tiles gq*10 .. gq*10+9
    f16x8 af[5];
#pragma unroll
    for (int ks = 0; ks < 5; ks++)
        af[ks] = *(const f16x8*)&XU[(msub * 16 + ncl) * 168 + ks * 32 + kg8];

    float xf = 0.f;
    for (int t10 = 0; t10 < 10; t10++) {
        const int nt = gq * 10 + t10;
        const _Float16* bp = Bp + ((size_t)nt * 5 * 16) * 32;
        f32x4 a = {0.f, 0.f, 0.f, 0.f};
#pragma unroll
        for (int ks = 0; ks < 5; ks++) {
            f16x8 br = *(const f16x8*)&bp[(ks * 16 + ncl) * 32 + kg8];
            a = __builtin_amdgcn_mfma_f32_16x16x32_f16(br, af[ks], a, 0, 0, 0);
        }
        float2 tb[4];
#pragma unroll
        for (int r = 0; r < 4; r++) tb[r] = tblg[nt * 16 + g4 * 4 + r];
#pragma unroll
        for (int r = 0; r < 4; r++)
            xf = fmaf(fmaxf(a[r] + tb[r].x, 0.f), tb[r].y, xf);
    }
    xf += __shfl_xor(xf, 16, 64);
    xf += __shfl_xor(xf, 32, 64);
    if (lane < 16) xfp[w][lane] = xf;
    __syncthreads();
    if (tid < 64) {
        const int ms = tid >> 4, j = tid & 15;
        sc[m0 + ms * 16 + j] = xfp[ms][j] + xfp[ms + 4][j];
    }
}

// ============ k_att: att (0..799) + S-copy (800..889); 512 thr ============
__global__ __launch_bounds__(512)
void k_att(const float* __restrict__ Sf, const float* __restrict__ Qf,
           const float* __restrict__ S, const float* __restrict__ Q,
           const float* __restrict__ sc, const float* __restrict__ convf_b,
           float* __restrict__ out, float* __restrict__ Scopy) {
    __shared__ float Sft[25][232];
    __shared__ float Ls[8][25];
    const int bid = blockIdx.x, tid = threadIdx.x;
    if (bid >= NB_ATT) {
        int g = (bid - NB_ATT) * 512 + tid;
        if (g < 46000) ((float4*)Scopy)[g] = ((const float4*)S)[g];
        return;
    }
    const int lane = tid & 63, wv = tid >> 6;   // wv 0..7
    const int qg = bid % 25;
    const int nq = (bid / 25) & 3;
    const int b  = bid / 100;
    const int q  = qg * 8 + wv, n0 = nq * 5;
    const float LOG2E = 1.4426950408889634f;
    const float bf0 = convf_b[0];

    const float* sfb = Sf + ((size_t)b * 100 + n0 * 5) * DD;
    for (int e = tid; e < 25 * DD; e += 512) Sft[e / DD][e % DD] = sfb[e];
    __syncthreads();

    float qf[4];
    const float* qfp = Qf + ((size_t)b * NQ + q) * DD;
#pragma unroll
    for (int i = 0; i < 4; i++) {
        int d = lane + 64 * i;
        qf[i] = (d < DD) ? qfp[d] : 0.f;
    }
    for (int idx = 0; idx < 25; idx++) {
        float racc = 0.f;
#pragma unroll
        for (int i = 0; i < 4; i++) {
            int d = lane + 64 * i;
            float s = (d < DD) ? Sft[idx][d] : 0.f;
            float e = __builtin_amdgcn_exp2f(s * qf[i]);
            racc += __builtin_amdgcn_rcpf(e + 1.f);
        }
#pragma unroll
        for (int off = 32; off > 0; off >>= 1) racc += __shfl_xor(racc, off, 64);
        if (lane == 0) Ls[wv][idx] = fmaf(-2.f, racc, 256.f);
    }

    float qr[4];
    const float* qp = Q + ((size_t)b * NQ + q) * DD;
#pragma unroll
    for (int i = 0; i < 4; i++) {
        int d = lane + 64 * i;
        qr[i] = (d < DD) ? qp[d] : 0.f;
    }
    for (int nl = 0; nl < 5; nl++) {
        const float* lp = Ls[wv] + nl * 5;
        float v0 = lp[0], v1 = lp[1], v2 = lp[2], v3 = lp[3], v4 = lp[4];
        float m = fmaxf(fmaxf(fmaxf(v0, v1), fmaxf(v2, v3)), v4);
        float e0 = __builtin_amdgcn_exp2f((v0 - m) * LOG2E);
        float e1 = __builtin_amdgcn_exp2f((v1 - m) * LOG2E);
        float e2 = __builtin_amdgcn_exp2f((v2 - m) * LOG2E);
        float e3 = __builtin_amdgcn_exp2f((v3 - m) * LOG2E);
        float e4 = __builtin_amdgcn_exp2f((v4 - m) * LOG2E);
        float inv = __builtin_amdgcn_rcpf(e0 + e1 + e2 + e3 + e4);
        float a0 = e0 * inv, a1 = e1 * inv, a2 = e2 * inv, a3 = e3 * inv, a4 = e4 * inv;
        const int n = n0 + nl;
        const float* spn = S + (size_t)(b * NN + n) * KK * DD;
        const float* s0 = sc + (size_t)(b * NN + n) * DD;
        float acc = 0.f;
#pragma unroll
        for (int i = 0; i < 4; i++) {
            int d = lane + 64 * i;
            if (d < DD) {
                float rep = a0 * spn[d] + a1 * spn[DD + d] + a2 * spn[2 * DD + d]
                          + a3 * spn[3 * DD + d] + a4 * spn[4 * DD + d];
                float df = rep - qr[i];
                float scw = fmaxf(s0[d] + bf0, 0.f) * 700.f;
                acc = fmaf(df * df, scw, acc);
            }
        }
#pragma unroll
        for (int off = 32; off > 0; off >>= 1) acc += __shfl_xor(acc, off, 64);
        if (lane == 0) out[((size_t)b * NQ + q) * NN + n] = -acc;
    }
}

extern "C" void kernel_launch(void* const* d_in, const int* in_sizes, int n_in,
                              void* d_out, int out_size, void* d_ws, size_t ws_size,
                              hipStream_t stream) {
    const float* S       = (const float*)d_in[0];
    const float* Q       = (const float*)d_in[1];
    const float* fc_w    = (const float*)d_in[2];
    const float* fc_b    = (const float*)d_in[3];
    const float* conv1_w = (const float*)d_in[4];
    const float* conv1_b = (const float*)d_in[5];
    const float* conv2_w = (const float*)d_in[6];
    const float* conv2_b = (const float*)d_in[7];
    const float* convf_w = (const float*)d_in[8];
    const float* convf_b = (const float*)d_in[9];
    float* out = (float*)d_out;

    float* ws = (float*)d_ws;
    float* Sf  = ws;                               // 184000 dwords
    float* Qf  = Sf + 184000;                      // 368000
    float* sc  = Qf + 368000;                      // 36800
    _Float16* Bp  = (_Float16*)(sc + 36800);       // 51200 f16 (25600 dw)
    _Float16* Bfc = Bp + 51200;                    // 61440 f16 (30720 dw)
    float2* tblg  = (float2*)(Bfc + 61440);        // 640 dw

    k_pre<<<NB_BFC + NB_BP, 256, 0, stream>>>(
        fc_w, conv2_w, conv2_b, convf_w, Bfc, Bp, tblg);
    k_main<<<NB_CONV + NB_FC2, 512, 0, stream>>>(
        S, Q, conv1_w, conv1_b, Bp, Bfc, tblg, sc, fc_b, Sf, Qf);
    k_att<<<NB_ATT + NB_CP, 512, 0, stream>>>(
        Sf, Qf, S, Q, sc, convf_b, out, out + (size_t)BB * NQ * NN);
}